// Round 1
// baseline (340.059 us; speedup 1.0000x reference)
//
#include <hip/hip_runtime.h>
#include <hip/hip_bf16.h>

#define SPA 110592            // D*H*W = 48*48*48
#define NPOS 221184           // B * SPA
#define NELEM 14155776        // B*C*SPA
#define KCODES 256
#define CCH 64

// ---------------- init: zero accumulators, precompute ||e_k||^2 ----------------
__global__ __launch_bounds__(256) void vq_init(
    const float* __restrict__ emb, float* __restrict__ en2,
    float* __restrict__ dw, float* __restrict__ hist, float* __restrict__ loss)
{
    int t = blockIdx.x * 256 + threadIdx.x;   // grid 64 blocks -> 16384 threads
    if (t < 16384) dw[t] = 0.f;
    if (t < KCODES) {
        const float* e = emb + (t << 6);
        float s = 0.f;
#pragma unroll
        for (int c = 0; c < CCH; ++c) s = fmaf(e[c], e[c], s);
        en2[t] = s;
        hist[t] = 0.f;
    }
    if (t == 0) loss[0] = 0.f;
}

// ---------------- main: argmin + quantize + enc_idx + histogram + loss ----------------
__global__ __launch_bounds__(256) void vq_argmin(
    const float* __restrict__ in, const float* __restrict__ emb,
    const float* __restrict__ en2, float* __restrict__ qout,
    float* __restrict__ encout, float* __restrict__ hist,
    float* __restrict__ loss)
{
    __shared__ float lhist[KCODES];
    int tid = threadIdx.x;
    lhist[tid] = 0.f;
    __syncthreads();

    int n = blockIdx.x * 256 + tid;           // 864 blocks * 256 = NPOS exactly
    int b = n / SPA;
    int s = n - b * SPA;
    const float* xp = in + b * (CCH * SPA) + s;

    float x[CCH];
#pragma unroll
    for (int c = 0; c < CCH; ++c) x[c] = xp[c * SPA];

    float x2 = 0.f;
#pragma unroll
    for (int c = 0; c < CCH; ++c) x2 = fmaf(x[c], x[c], x2);

    float bestd = 3.402823466e38f;
    int bestk = 0;
    for (int k = 0; k < KCODES; ++k) {
        const float* e = emb + (k << 6);      // uniform address -> scalar loads
        float a0 = 0.f, a1 = 0.f, a2 = 0.f, a3 = 0.f;
#pragma unroll
        for (int c = 0; c < CCH; c += 4) {
            a0 = fmaf(x[c + 0], e[c + 0], a0);
            a1 = fmaf(x[c + 1], e[c + 1], a1);
            a2 = fmaf(x[c + 2], e[c + 2], a2);
            a3 = fmaf(x[c + 3], e[c + 3], a3);
        }
        float dot = (a0 + a1) + (a2 + a3);
        float dist = (x2 + en2[k]) - 2.f * dot;
        if (dist < bestd) { bestd = dist; bestk = k; }   // strict < keeps first min
    }

    // histogram (LDS aggregate, flush once per block)
    atomicAdd(&lhist[bestk], 1.0f);

    // quantized write + commitment loss
    const float* eb = emb + (bestk << 6);     // per-lane gather, table is L1/L2 hot
    float* qp = qout + b * (CCH * SPA) + s;
    float lsum = 0.f;
#pragma unroll
    for (int c = 0; c < CCH; ++c) {
        float q = eb[c];
        float d = q - x[c];
        lsum = fmaf(d, d, lsum);
        qp[c * SPA] = q;
    }
    encout[n] = (float)bestk;

    // wave reduce loss, one atomic per wave
    for (int off = 32; off > 0; off >>= 1) lsum += __shfl_down(lsum, off, 64);
    if ((tid & 63) == 0)
        unsafeAtomicAdd(loss, lsum * (2.5f / 14155776.f));

    __syncthreads();
    unsafeAtomicAdd(&hist[tid], lhist[tid]);
}

// ---------------- dw = segment_sum(flat_input by index) ----------------
// LDS layout [c][k ^ (c&31)]: exactly 64KB, bank-conflict-free in both phases.
__global__ __launch_bounds__(256) void vq_dw(
    const float* __restrict__ in, const float* __restrict__ encout,
    float* __restrict__ dw)
{
    __shared__ float l[CCH * KCODES];
    int tid = threadIdx.x;
    for (int i = tid; i < CCH * KCODES; i += 256) l[i] = 0.f;
    __syncthreads();

    for (int n = blockIdx.x * 256 + tid; n < NPOS; n += 256 * 256) {
        int b = n / SPA;
        int s = n - b * SPA;
        int k = (int)encout[n];
        const float* xp = in + b * (CCH * SPA) + s;
#pragma unroll
        for (int c = 0; c < CCH; ++c) {
            atomicAdd(&l[(c << 8) + (k ^ (c & 31))], xp[c * SPA]);
        }
    }
    __syncthreads();

    for (int i = tid; i < CCH * KCODES; i += 256) {
        int k = i >> 6, c = i & 63;           // i = k*64 + c : coalesced global atomics
        float v = l[(c << 8) + (k ^ (c & 31))];
        unsafeAtomicAdd(&dw[i], v);
    }
}

// ---------------- EMA finalize ----------------
__global__ __launch_bounds__(256) void vq_ema(
    const float* __restrict__ csize, const float* __restrict__ emaw,
    const float* __restrict__ hist, const float* __restrict__ dw,
    float* __restrict__ embo)
{
    __shared__ float red[KCODES];
    int t = threadIdx.x;
    float ncs = 0.99f * csize[t] + 0.01f * hist[t];
    red[t] = ncs;
    __syncthreads();
    for (int off = 128; off > 0; off >>= 1) {
        if (t < off) red[t] += red[t + off];
        __syncthreads();
    }
    float nsum = red[0];
    float w = (ncs + 1e-5f) / (nsum + 256.f * 1e-5f) * nsum;
#pragma unroll
    for (int c = 0; c < CCH; ++c) {
        int i = (t << 6) + c;
        float nw = 0.99f * emaw[i] + 0.01f * dw[i];
        embo[i] = nw / w;
    }
}

extern "C" void kernel_launch(void* const* d_in, const int* in_sizes, int n_in,
                              void* d_out, int out_size, void* d_ws, size_t ws_size,
                              hipStream_t stream)
{
    const float* in   = (const float*)d_in[0];
    const float* emb  = (const float*)d_in[1];
    const float* cs   = (const float*)d_in[2];
    const float* emaw = (const float*)d_in[3];

    float* out  = (float*)d_out;
    float* qout = out;                         // 14,155,776
    float* loss = out + NELEM;                 // 1
    float* enc  = loss + 1;                    // 221,184
    float* hist = enc + NPOS;                  // 256  (== encodings_sum output)
    float* embo = hist + KCODES;               // 16,384

    float* en2 = (float*)d_ws;                 // 256
    float* dw  = en2 + KCODES;                 // 16,384

    vq_init<<<dim3(64), dim3(256), 0, stream>>>(emb, en2, dw, hist, loss);
    vq_argmin<<<dim3(864), dim3(256), 0, stream>>>(in, emb, en2, qout, enc, hist, loss);
    vq_dw<<<dim3(256), dim3(256), 0, stream>>>(in, enc, dw);
    vq_ema<<<dim3(1), dim3(256), 0, stream>>>(cs, emaw, hist, dw, embo);
}